// Round 17
// baseline (63.875 us; speedup 1.0000x reference)
//
#include <hip/hip_runtime.h>

// TT embedding gather, vocab 125000 = 50*50*50, emb 512 = 8*8*8.
// out[m,n,p] = sum_{r,s} g1[m,r] g2[r,n,s] g3[s,p]
// Pipeline (3 graph nodes; cooperative grid.sync REJECTED — R12: ~250us barrier
// cost on 8 non-coherent XCDs):
//   1. hipMemsetAsync(hist, 0)
//   2. tt_bucket (452 blocks — R17: g2/g3 conversions moved INLINE into Phase A):
//      scatter: key=(table, i2*50+i3); pos=atomicAdd(hist[key]);
//      bucket[key*MAXC+pos] = lid | (i1<<17).  Tail 100 blocks: g1 -> bf16.
//   3. tt_group: one block (4 waves) per key (5000 = 8*625; R13 coarser and R15
//      finer both regressed — measured optimum). XCD swizzle swz=(B&7)*625+(B>>3),
//      word/ctx interleave.
//      Early: hist count + wave's first bucket uint2 (hidden under Phase A).
//      Phase A (MFMA): T(256x8)=G2@G3 reading f32 g2/g3 DIRECTLY (2x float4 +
//        8x f2bf per tile for A; 8 scalar f32 + f2bf for the g3 B-frag, cols
//        8-15 zero) — same f2bf rounding as before, bit-identical results.
//        4x mfma_16x16x32_bf16/wave; D->bf16 -> LDS, COLUMN-PERMUTED B-frag
//        layout flat(np,r) = (np&3)*512 + ((r>>3)*16 + (np>>2))*8 + (r&7).
//      ONE __syncthreads.
//      Phase B: B-frags from LDS (16 VGPRs); per tile (2 lookups): prefetched
//        uint2 -> 1 dwordx4 g1 A-load -> 4x MFMA -> 4x float4 PLAIN stores
//        (R14: nt hint removed, +8.5us — nt defeats write combining here).
// Frag mappings (m89-verified): A row=l&15, k=8*(l>>4)+j; B col=l&15, k=8*(l>>4)+j;
//                               D col=l&15, row=(l>>4)*4+q.
// R9 lesson: never pull >100 live values through s_load. R16 lesson: deeper
// Phase-B pipelining is neutral — TLP already hides the g1 chain.

#define NFAC 50
#define TPAIR 2048
#define NPAIRS 2500
#define NKEYS 5000
#define MAXC 192
#define NWORD 8192
#define NCTX  81920
#define NLOOK (NWORD + NCTX)
#define NBB   ((NLOOK + 255) / 256)          // 352 (exact: 352*256 == NLOOK)
#define NVB   (NBB + 100)                    // bucket-kernel blocks (scatter + g1 cvt)

typedef short short8 __attribute__((ext_vector_type(8)));   // 8 bf16 (4 VGPRs)
typedef float f32x4v __attribute__((ext_vector_type(4)));

__device__ __forceinline__ unsigned short f2bf(float f) {   // RNE f32 -> bf16 bits
    unsigned u = __builtin_bit_cast(unsigned, f);
    u += 0x7FFFu + ((u >> 16) & 1u);
    return (unsigned short)(u >> 16);
}

__device__ __forceinline__ int pair_of(int idx) {
    const int i3 = idx % NFAC;
    const int i2 = (idx / NFAC) % NFAC;
    return i2 * NFAC + i3;
}

// ---------------- bucket scatter + g1 conversion ----------------

__global__ __launch_bounds__(256) void tt_bucket(
    const int* __restrict__ widx, const int* __restrict__ cidx,
    const float* __restrict__ w1, const float* __restrict__ c1,
    int* __restrict__ hist, unsigned* __restrict__ bucket,
    unsigned short* __restrict__ g1w, unsigned short* __restrict__ g1c)
{
    const int vb = blockIdx.x;
    const int t = threadIdx.x;
    if (vb < NBB) {                                  // bucket scatter
        const int g = vb * 256 + t;                  // < NLOOK exactly
        const int idx = (g < NWORD) ? widx[g] : cidx[g - NWORD];
        const int key = (g < NWORD ? 0 : NPAIRS) + pair_of(idx);
        const int i1  = idx / (NFAC * NFAC);
        const int pos = atomicAdd(&hist[key], 1);
        if (pos < MAXC)
            bucket[(size_t)key * MAXC + pos] = (unsigned)g | ((unsigned)i1 << 17);
    } else {                                         // g1 -> bf16 (25600 elems)
        const int g = (vb - NBB) * 256 + t;
        if (g < 12800) g1w[g] = f2bf(w1[g]);
        else           g1c[g - 12800] = f2bf(c1[g - 12800]);
    }
}

// ---------------- group kernel: one block per key ----------------

__global__ __launch_bounds__(256, 8) void tt_group(
    const unsigned* __restrict__ bucket, const int* __restrict__ hist,
    const unsigned short* __restrict__ g1w, const unsigned short* __restrict__ g1c,
    const float* __restrict__ w2, const float* __restrict__ c2,
    const float* __restrict__ w3, const float* __restrict__ c3,
    float* __restrict__ out)
{
    const int B = blockIdx.x;
    const int swz = (B & 7) * (NKEYS / 8) + (B >> 3);   // XCD-chunked bijective
    const int key = (swz & 1) ? ((swz >> 1) + NPAIRS) : (swz >> 1);

    const int t = threadIdx.x;
    const int wave = t >> 6;
    const int lane = t & 63;
    const int l15 = lane & 15;
    const int kg  = lane >> 4;
    const int sel = (lane >> 3) & 1;
    const int am  = lane & 7;

    // ---- early loads (hidden under Phase A) ----
    int count = hist[key];
    if (count == 0) return;
    if (count > MAXC) count = MAXC;
    const unsigned* kb = bucket + (size_t)key * MAXC;
    uint2 pre = make_uint2(0u, 0u);
    if (wave < ((count + 1) >> 1)) pre = *reinterpret_cast<const uint2*>(kb + 2 * wave);

    const bool isCtx = key >= NPAIRS;
    const int pair = isCtx ? key - NPAIRS : key;
    const unsigned short* g1t = isCtx ? g1c : g1w;
    const float* g2f = isCtx ? c2 : w2;
    const float* g3f = isCtx ? c3 : w3;
    const int i2 = pair / NFAC, i3 = pair % NFAC;

    __shared__ unsigned short tl[TPAIR];

    // ---- Phase A: T = G2 @ G3 via MFMA -> LDS (f32 inputs, inline f2bf) ----
    {
        short8 bg3 = {};
        if (l15 < 8) {                               // cols 8-15 are zero
            const float* g3p = g3f + i3 * 256;       // [s][p]
            #pragma unroll
            for (int j = 0; j < 8; ++j)
                bg3[j] = (short)f2bf(g3p[(8 * kg + j) * 8 + l15]);
        }
        const float* g2p = g2f + i2 * 8192;          // [rn][s], rn = r*8+n
        #pragma unroll
        for (int tile = 0; tile < 4; ++tile) {
            const int rbase = wave * 64 + tile * 16;
            const float* ap = g2p + (rbase + l15) * 32 + kg * 8;
            const float4 va = reinterpret_cast<const float4*>(ap)[0];
            const float4 vb = reinterpret_cast<const float4*>(ap)[1];
            short8 a;
            a[0] = (short)f2bf(va.x); a[1] = (short)f2bf(va.y);
            a[2] = (short)f2bf(va.z); a[3] = (short)f2bf(va.w);
            a[4] = (short)f2bf(vb.x); a[5] = (short)f2bf(vb.y);
            a[6] = (short)f2bf(vb.z); a[7] = (short)f2bf(vb.w);
            const f32x4v z = {0.f, 0.f, 0.f, 0.f};
            const f32x4v d = __builtin_amdgcn_mfma_f32_16x16x32_bf16(a, bg3, z, 0, 0, 0);
            if (l15 < 8) {
                const int pp = l15;
                #pragma unroll
                for (int q = 0; q < 4; ++q) {
                    const int rn = rbase + kg * 4 + q;
                    const int r = rn >> 3, n = rn & 7;
                    const int np = n * 8 + pp;
                    const int flat = (np & 3) * 512 + ((r >> 3) * 16 + (np >> 2)) * 8 + (r & 7);
                    tl[flat] = f2bf(d[q]);
                }
            }
        }
    }
    __syncthreads();                                  // single barrier

    // ---- Phase B: MFMA over the group's lookups ----
    const short8 b0 = *reinterpret_cast<const short8*>(&tl[0 * 512 + lane * 8]);
    const short8 b1 = *reinterpret_cast<const short8*>(&tl[1 * 512 + lane * 8]);
    const short8 b2 = *reinterpret_cast<const short8*>(&tl[2 * 512 + lane * 8]);
    const short8 b3 = *reinterpret_cast<const short8*>(&tl[3 * 512 + lane * 8]);

    const int ntile = (count + 1) >> 1;
    uint2 pkc = pre;
    for (int jt = wave; jt < ntile; jt += 4) {
        const int jn = jt + 4;
        uint2 pkn = pkc;
        if (jn < ntile) pkn = *reinterpret_cast<const uint2*>(kb + 2 * jn);

        const bool has2 = (2 * jt + 1) < count;
        const unsigned pk0 = __builtin_amdgcn_readfirstlane(pkc.x);
        const unsigned pk1 = has2 ? __builtin_amdgcn_readfirstlane(pkc.y) : pk0;
        const int lid0 = pk0 & 0x1FFFF, i10 = pk0 >> 17;
        const int lid1 = pk1 & 0x1FFFF, i11 = pk1 >> 17;

        const short8 a = *reinterpret_cast<const short8*>(
            g1t + (sel ? i11 : i10) * 256 + am * 32 + kg * 8);

        const f32x4v z = {0.f, 0.f, 0.f, 0.f};
        const f32x4v d0 = __builtin_amdgcn_mfma_f32_16x16x32_bf16(a, b0, z, 0, 0, 0);
        const f32x4v d1 = __builtin_amdgcn_mfma_f32_16x16x32_bf16(a, b1, z, 0, 0, 0);
        const f32x4v d2 = __builtin_amdgcn_mfma_f32_16x16x32_bf16(a, b2, z, 0, 0, 0);
        const f32x4v d3 = __builtin_amdgcn_mfma_f32_16x16x32_bf16(a, b3, z, 0, 0, 0);

        float* o0 = out + (size_t)lid0 * 512;
        float* o1 = out + (size_t)lid1 * 512;
        #pragma unroll
        for (int q = 0; q < 4; ++q) {
            const int row = kg * 4 + q;              // 0..15 = (lookup, m)
            const int mm = row & 7;
            float* ob = (row >= 8) ? o1 : o0;
            if (row < 8 || has2) {
                f32x4v v; v[0] = d0[q]; v[1] = d1[q]; v[2] = d2[q]; v[3] = d3[q];
                *reinterpret_cast<f32x4v*>(ob + mm * 64 + 4 * l15) = v;   // plain store
            }
        }
        pkc = pkn;
    }
}

// ---------------- fallback: fully fused f32 (tiny ws) ----------------

__global__ __launch_bounds__(512) void tt_fused(
    const int* __restrict__ word_idx, const int* __restrict__ ctx_idx,
    const float* __restrict__ w1, const float* __restrict__ w2, const float* __restrict__ w3,
    const float* __restrict__ c1, const float* __restrict__ c2, const float* __restrict__ c3,
    float* __restrict__ out)
{
    const int b = blockIdx.x;
    int idx; const float *k1, *k2, *k3; float* o;
    if (b < NWORD) { idx = word_idx[b]; k1 = w1; k2 = w2; k3 = w3; o = out + (size_t)b * 512; }
    else { const int c = b - NWORD; idx = ctx_idx[c]; k1 = c1; k2 = c2; k3 = c3;
           o = out + (size_t)(NWORD + c) * 512; }
    const int i3 = idx % NFAC;
    const int rem = idx / NFAC;
    const int i2 = rem % NFAC;
    const int i1 = rem / NFAC;

    __shared__ float g3s[256];
    __shared__ float g1s[256];
    __shared__ float Ts[TPAIR];
    const int t = threadIdx.x;
    if (t < 256) g3s[t] = k3[i3 * 256 + t];
    else         g1s[t - 256] = k1[i1 * 256 + (t - 256)];
    __syncthreads();

    {
        const int e0 = t * 4;
        const int r = e0 >> 6, n = (e0 >> 3) & 7, p0 = e0 & 7;
        const float* g2row = k2 + i2 * 8192 + r * 256 + n * 32;
        float acc[4] = {0.f,0.f,0.f,0.f};
        #pragma unroll
        for (int s = 0; s < 32; ++s) {
            const float v = g2row[s];
            #pragma unroll
            for (int j = 0; j < 4; ++j) acc[j] += v * g3s[s * 8 + p0 + j];
        }
        reinterpret_cast<float4*>(Ts + e0)[0] = make_float4(acc[0], acc[1], acc[2], acc[3]);
    }
    __syncthreads();

    const int m = t >> 6, np = t & 63;
    float acc = 0.f;
    #pragma unroll
    for (int r = 0; r < 32; ++r)
        acc += g1s[m * 32 + r] * Ts[r * 64 + np];
    o[m * 64 + np] = acc;
}

extern "C" void kernel_launch(void* const* d_in, const int* in_sizes, int n_in,
                              void* d_out, int out_size, void* d_ws, size_t ws_size,
                              hipStream_t stream) {
    const int*   widx = (const int*)d_in[0];
    const int*   cidx = (const int*)d_in[1];
    const float* w1   = (const float*)d_in[2];
    const float* w2   = (const float*)d_in[3];
    const float* w3   = (const float*)d_in[4];
    const float* c1   = (const float*)d_in[5];
    const float* c2   = (const float*)d_in[6];
    const float* c3   = (const float*)d_in[7];
    float* out = (float*)d_out;

    // ws: g1w,g1c bf16 (2 x 25,600 B); hist (20,000 B); bucket (3,840,000 B)
    const size_t need = 2 * 25600 + NKEYS * 4 + (size_t)NKEYS * MAXC * 4;

    if (ws_size >= need) {
        unsigned short* g1wb = (unsigned short*)d_ws;
        unsigned short* g1cb = g1wb + 12800;
        int*      hist   = (int*)(g1cb + 12800);
        unsigned* bucket = (unsigned*)(hist + NKEYS);

        hipMemsetAsync(hist, 0, NKEYS * sizeof(int), stream);
        tt_bucket<<<NVB, 256, 0, stream>>>(widx, cidx, w1, c1,
                                           hist, bucket, g1wb, g1cb);
        tt_group<<<NKEYS, 256, 0, stream>>>(bucket, hist, g1wb, g1cb,
                                            w2, c2, w3, c3, out);
    } else {
        tt_fused<<<NLOOK, 512, 0, stream>>>(widx, cidx, w1, w2, w3, c1, c2, c3, out);
    }
}

// Round 18
// 53.263 us; speedup vs baseline: 1.1992x; 1.1992x over previous
//
#include <hip/hip_runtime.h>

// TT embedding gather, vocab 125000 = 50*50*50, emb 512 = 8*8*8.
// out[m,n,p] = sum_{r,s} g1[m,r] g2[r,n,s] g3[s,p]
// MEASURED-BEST configuration (R14, 53.4us). Bracketing experiments all lost:
//   R13 2-keys/block: 63.5 | R15 split ctx keys: 55.5 | R16 deeper pipeline: 54.2
//   R17 inline g2/g3 cvt in Phase A: 63.9 | R12 cooperative grid.sync: 321 (us!)
// Pipeline (3 graph nodes):
//   1. hipMemsetAsync(hist, 0)   (irreducible: hist must be zero per replay)
//   2. tt_bucket: per lookup, key=(table, i2*50+i3); pos=atomicAdd(hist[key]);
//      bucket[key*MAXC+pos] = lid | (i1<<17). Tail blocks: g1,g2 -> bf16;
//      g3 MFMA B-fragments (cols 8-15 = 0).  (Pre-conversion amortizes: R17
//      proved per-key inline conversion costs 2x traffic + repeated VALU.)
//   3. tt_group: one block (4 waves) per key (5000 = 8*625).
//      XCD swizzle swz=(B&7)*625+(B>>3), word/ctx interleave.
//      Early: hist count + wave's first bucket uint2 (hidden under Phase A).
//      Phase A (MFMA): T(256x8)=G2@G3, 4x mfma_16x16x32_bf16/wave,
//        D->bf16 -> LDS, COLUMN-PERMUTED B-frag layout
//        flat(np,r) = (np&3)*512 + ((r>>3)*16 + (np>>2))*8 + (r&7).
//      ONE __syncthreads.
//      Phase B: B-frags from LDS (16 VGPRs); per tile (2 lookups): prefetched
//        uint2 -> 1 dwordx4 g1 A-load -> 4x MFMA -> 4x float4 PLAIN stores
//        (R14: nt hint removed, +8.5us — nt defeats write combining on gfx950).
// Frag mappings (m89-verified): A row=l&15, k=8*(l>>4)+j; B col=l&15, k=8*(l>>4)+j;
//                               D col=l&15, row=(l>>4)*4+q.
// Lessons: R9 never pull >100 live values through s_load; R16 TLP already hides
// the g1 chain; remaining gap is scattered-2KB-row write-stream efficiency
// (~0.7 of sequential fill BW) — intrinsic to grouped-by-key output placement.

#define NFAC 50
#define TPAIR 2048
#define NPAIRS 2500
#define NKEYS 5000
#define MAXC 192
#define NWORD 8192
#define NCTX  81920
#define NLOOK (NWORD + NCTX)
#define NBB   ((NLOOK + 255) / 256)          // 352 (exact: 352*256 == NLOOK)
#define NE2   409600                         // floats per g2 table (50*32*8*32)
#define NVB   (NBB + 1100)                   // bucket-kernel virtual blocks

typedef short short8 __attribute__((ext_vector_type(8)));   // 8 bf16 (4 VGPRs)
typedef float f32x4v __attribute__((ext_vector_type(4)));
typedef unsigned short us4 __attribute__((ext_vector_type(4)));

__device__ __forceinline__ unsigned short f2bf(float f) {   // RNE f32 -> bf16 bits
    unsigned u = __builtin_bit_cast(unsigned, f);
    u += 0x7FFFu + ((u >> 16) & 1u);
    return (unsigned short)(u >> 16);
}

__device__ __forceinline__ int pair_of(int idx) {
    const int i3 = idx % NFAC;
    const int i2 = (idx / NFAC) % NFAC;
    return i2 * NFAC + i3;
}

// ---------------- bucket scatter + conversions ----------------

__global__ __launch_bounds__(256) void tt_bucket(
    const int* __restrict__ widx, const int* __restrict__ cidx,
    const float* __restrict__ w1, const float* __restrict__ c1,
    const float* __restrict__ w2, const float* __restrict__ c2,
    const float* __restrict__ w3, const float* __restrict__ c3,
    int* __restrict__ hist, unsigned* __restrict__ bucket,
    unsigned short* __restrict__ g1w, unsigned short* __restrict__ g1c,
    unsigned short* __restrict__ g2w, unsigned short* __restrict__ g2c,
    unsigned short* __restrict__ g3w, unsigned short* __restrict__ g3c)
{
    const int vb = blockIdx.x;
    const int t = threadIdx.x;
    if (vb < NBB) {                                  // bucket scatter
        const int g = vb * 256 + t;                  // < NLOOK exactly
        const int idx = (g < NWORD) ? widx[g] : cidx[g - NWORD];
        const int key = (g < NWORD ? 0 : NPAIRS) + pair_of(idx);
        const int i1  = idx / (NFAC * NFAC);
        const int pos = atomicAdd(&hist[key], 1);
        if (pos < MAXC)
            bucket[(size_t)key * MAXC + pos] = (unsigned)g | ((unsigned)i1 << 17);
    } else if (vb < NBB + 800) {                     // g2 -> bf16, 4 elems/thread
        const int gid = (vb - NBB) * 256 + t;        // 0..204799
        const int e = gid * 4;
        const float* src; unsigned short* dst; int off;
        if (e < NE2) { src = w2; dst = g2w; off = e; }
        else         { src = c2; dst = g2c; off = e - NE2; }
        const float4 v = *reinterpret_cast<const float4*>(src + off);
        us4 o; o[0] = f2bf(v.x); o[1] = f2bf(v.y); o[2] = f2bf(v.z); o[3] = f2bf(v.w);
        *reinterpret_cast<us4*>(dst + off) = o;
    } else if (vb < NBB + 900) {                     // g1 -> bf16
        const int g = (vb - NBB - 800) * 256 + t;    // 0..25599
        if (g < 12800) g1w[g] = f2bf(w1[g]);
        else           g1c[g - 12800] = f2bf(c1[g - 12800]);
    } else {                                         // g3 B-fragments (cols 8-15 = 0)
        const int g = (vb - NBB - 900) * 256 + t;    // 0..51199
        const int tab = g / 25600;
        const int rem = g - tab * 25600;
        const int i3 = rem >> 9, le = rem & 511;
        const int l = le >> 3, j = le & 7;
        const int col = l & 15, k = 8 * (l >> 4) + j;
        const float* src = tab ? c3 : w3;
        unsigned short* dst = tab ? g3c : g3w;
        dst[i3 * 512 + le] = (col < 8) ? f2bf(src[i3 * 256 + k * 8 + col]) : 0;
    }
}

// ---------------- group kernel: one block per key (measured optimum) ----------------

__global__ __launch_bounds__(256, 8) void tt_group(
    const unsigned* __restrict__ bucket, const int* __restrict__ hist,
    const unsigned short* __restrict__ g1w, const unsigned short* __restrict__ g1c,
    const unsigned short* __restrict__ g2w, const unsigned short* __restrict__ g2c,
    const unsigned short* __restrict__ g3w, const unsigned short* __restrict__ g3c,
    float* __restrict__ out)
{
    const int B = blockIdx.x;
    const int swz = (B & 7) * (NKEYS / 8) + (B >> 3);   // XCD-chunked bijective
    const int key = (swz & 1) ? ((swz >> 1) + NPAIRS) : (swz >> 1);

    const int t = threadIdx.x;
    const int wave = t >> 6;
    const int lane = t & 63;
    const int l15 = lane & 15;
    const int kg  = lane >> 4;
    const int sel = (lane >> 3) & 1;
    const int am  = lane & 7;

    // ---- early loads (hidden under Phase A) ----
    int count = hist[key];
    if (count == 0) return;
    if (count > MAXC) count = MAXC;
    const unsigned* kb = bucket + (size_t)key * MAXC;
    uint2 pre = make_uint2(0u, 0u);
    if (wave < ((count + 1) >> 1)) pre = *reinterpret_cast<const uint2*>(kb + 2 * wave);

    const bool isCtx = key >= NPAIRS;
    const int pair = isCtx ? key - NPAIRS : key;
    const unsigned short* g1t = isCtx ? g1c : g1w;
    const unsigned short* g2t = isCtx ? g2c : g2w;
    const unsigned short* g3t = isCtx ? g3c : g3w;
    const int i2 = pair / NFAC, i3 = pair % NFAC;

    __shared__ unsigned short tl[TPAIR];

    // ---- Phase A: T = G2 @ G3 via MFMA -> LDS ----
    {
        const short8 bg3 = *reinterpret_cast<const short8*>(g3t + i3 * 512 + lane * 8);
        const unsigned short* g2p = g2t + i2 * 8192;
        #pragma unroll
        for (int tile = 0; tile < 4; ++tile) {
            const int rbase = wave * 64 + tile * 16;
            const short8 a = *reinterpret_cast<const short8*>(
                g2p + (rbase + l15) * 32 + kg * 8);
            const f32x4v z = {0.f, 0.f, 0.f, 0.f};
            const f32x4v d = __builtin_amdgcn_mfma_f32_16x16x32_bf16(a, bg3, z, 0, 0, 0);
            if (l15 < 8) {                            // cols 8-15 are zero-padding
                const int pp = l15;
                #pragma unroll
                for (int q = 0; q < 4; ++q) {
                    const int rn = rbase + kg * 4 + q;
                    const int r = rn >> 3, n = rn & 7;
                    const int np = n * 8 + pp;
                    const int flat = (np & 3) * 512 + ((r >> 3) * 16 + (np >> 2)) * 8 + (r & 7);
                    tl[flat] = f2bf(d[q]);
                }
            }
        }
    }
    __syncthreads();                                  // single barrier

    // ---- Phase B: MFMA over the group's lookups ----
    const short8 b0 = *reinterpret_cast<const short8*>(&tl[0 * 512 + lane * 8]);
    const short8 b1 = *reinterpret_cast<const short8*>(&tl[1 * 512 + lane * 8]);
    const short8 b2 = *reinterpret_cast<const short8*>(&tl[2 * 512 + lane * 8]);
    const short8 b3 = *reinterpret_cast<const short8*>(&tl[3 * 512 + lane * 8]);

    const int ntile = (count + 1) >> 1;
    uint2 pkc = pre;
    for (int jt = wave; jt < ntile; jt += 4) {
        const int jn = jt + 4;
        uint2 pkn = pkc;
        if (jn < ntile) pkn = *reinterpret_cast<const uint2*>(kb + 2 * jn);

        const bool has2 = (2 * jt + 1) < count;
        const unsigned pk0 = __builtin_amdgcn_readfirstlane(pkc.x);
        const unsigned pk1 = has2 ? __builtin_amdgcn_readfirstlane(pkc.y) : pk0;
        const int lid0 = pk0 & 0x1FFFF, i10 = pk0 >> 17;
        const int lid1 = pk1 & 0x1FFFF, i11 = pk1 >> 17;

        const short8 a = *reinterpret_cast<const short8*>(
            g1t + (sel ? i11 : i10) * 256 + am * 32 + kg * 8);

        const f32x4v z = {0.f, 0.f, 0.f, 0.f};
        const f32x4v d0 = __builtin_amdgcn_mfma_f32_16x16x32_bf16(a, b0, z, 0, 0, 0);
        const f32x4v d1 = __builtin_amdgcn_mfma_f32_16x16x32_bf16(a, b1, z, 0, 0, 0);
        const f32x4v d2 = __builtin_amdgcn_mfma_f32_16x16x32_bf16(a, b2, z, 0, 0, 0);
        const f32x4v d3 = __builtin_amdgcn_mfma_f32_16x16x32_bf16(a, b3, z, 0, 0, 0);

        float* o0 = out + (size_t)lid0 * 512;
        float* o1 = out + (size_t)lid1 * 512;
        #pragma unroll
        for (int q = 0; q < 4; ++q) {
            const int row = kg * 4 + q;              // 0..15 = (lookup, m)
            const int mm = row & 7;
            float* ob = (row >= 8) ? o1 : o0;
            if (row < 8 || has2) {
                f32x4v v; v[0] = d0[q]; v[1] = d1[q]; v[2] = d2[q]; v[3] = d3[q];
                *reinterpret_cast<f32x4v*>(ob + mm * 64 + 4 * l15) = v;   // plain store
            }
        }
        pkc = pkn;
    }
}

// ---------------- fallback: fully fused f32 (tiny ws) ----------------

__global__ __launch_bounds__(512) void tt_fused(
    const int* __restrict__ word_idx, const int* __restrict__ ctx_idx,
    const float* __restrict__ w1, const float* __restrict__ w2, const float* __restrict__ w3,
    const float* __restrict__ c1, const float* __restrict__ c2, const float* __restrict__ c3,
    float* __restrict__ out)
{
    const int b = blockIdx.x;
    int idx; const float *k1, *k2, *k3; float* o;
    if (b < NWORD) { idx = word_idx[b]; k1 = w1; k2 = w2; k3 = w3; o = out + (size_t)b * 512; }
    else { const int c = b - NWORD; idx = ctx_idx[c]; k1 = c1; k2 = c2; k3 = c3;
           o = out + (size_t)(NWORD + c) * 512; }
    const int i3 = idx % NFAC;
    const int rem = idx / NFAC;
    const int i2 = rem % NFAC;
    const int i1 = rem / NFAC;

    __shared__ float g3s[256];
    __shared__ float g1s[256];
    __shared__ float Ts[TPAIR];
    const int t = threadIdx.x;
    if (t < 256) g3s[t] = k3[i3 * 256 + t];
    else         g1s[t - 256] = k1[i1 * 256 + (t - 256)];
    __syncthreads();

    {
        const int e0 = t * 4;
        const int r = e0 >> 6, n = (e0 >> 3) & 7, p0 = e0 & 7;
        const float* g2row = k2 + i2 * 8192 + r * 256 + n * 32;
        float acc[4] = {0.f,0.f,0.f,0.f};
        #pragma unroll
        for (int s = 0; s < 32; ++s) {
            const float v = g2row[s];
            #pragma unroll
            for (int j = 0; j < 4; ++j) acc[j] += v * g3s[s * 8 + p0 + j];
        }
        reinterpret_cast<float4*>(Ts + e0)[0] = make_float4(acc[0], acc[1], acc[2], acc[3]);
    }
    __syncthreads();

    const int m = t >> 6, np = t & 63;
    float acc = 0.f;
    #pragma unroll
    for (int r = 0; r < 32; ++r)
        acc += g1s[m * 32 + r] * Ts[r * 64 + np];
    o[m * 64 + np] = acc;
}

extern "C" void kernel_launch(void* const* d_in, const int* in_sizes, int n_in,
                              void* d_out, int out_size, void* d_ws, size_t ws_size,
                              hipStream_t stream) {
    const int*   widx = (const int*)d_in[0];
    const int*   cidx = (const int*)d_in[1];
    const float* w1   = (const float*)d_in[2];
    const float* w2   = (const float*)d_in[3];
    const float* w3   = (const float*)d_in[4];
    const float* c1   = (const float*)d_in[5];
    const float* c2   = (const float*)d_in[6];
    const float* c3   = (const float*)d_in[7];
    float* out = (float*)d_out;

    // ws (ushorts): g1w 12800, g1c 12800, g2w 409600, g2c 409600, g3w 25600, g3c 25600
    //   = 896000 us = 1,792,000 B;  hist 20,000 B;  bucket 3,840,000 B  => ~5.7 MB
    const size_t need = 896000 * 2 + NKEYS * 4 + (size_t)NKEYS * MAXC * 4;

    if (ws_size >= need) {
        unsigned short* g1wb = (unsigned short*)d_ws;
        unsigned short* g1cb = g1wb + 12800;
        unsigned short* g2wb = g1cb + 12800;
        unsigned short* g2cb = g2wb + NE2;
        unsigned short* g3wb = g2cb + NE2;
        unsigned short* g3cb = g3wb + 25600;
        int*      hist   = (int*)(g3cb + 25600);
        unsigned* bucket = (unsigned*)(hist + NKEYS);

        hipMemsetAsync(hist, 0, NKEYS * sizeof(int), stream);
        tt_bucket<<<NVB, 256, 0, stream>>>(widx, cidx, w1, c1, w2, c2, w3, c3,
                                           hist, bucket, g1wb, g1cb, g2wb, g2cb,
                                           g3wb, g3cb);
        tt_group<<<NKEYS, 256, 0, stream>>>(bucket, hist, g1wb, g1cb,
                                            g2wb, g2cb, g3wb, g3cb, out);
    } else {
        tt_fused<<<NLOOK, 512, 0, stream>>>(widx, cidx, w1, w2, w3, c1, c2, c3, out);
    }
}